// Round 2
// baseline (19997.304 us; speedup 1.0000x reference)
//
#include <hip/hip_runtime.h>
#include <hip/hip_bf16.h>
#include <stdint.h>

// GRU B=64 T=512 I=512 H=1024, fp32 in/out.
// bf16 hi/lo 3-pass MFMA numerics (identical to round 1).
// Round 2: persistent cooperative recurrence kernel — weights LDS-resident,
// custom tree grid-barrier, 2 barriers/step, zero per-step launches.

#define B_ 64
#define T_ 512
#define I_ 512
#define H_ 1024
#define NWG_A 128
#define NWG_B 64
#define NWG 192
#define NBUCK 16
#define BUCK_SZ (NWG / NBUCK)

typedef __attribute__((ext_vector_type(4))) float f32x4;
typedef __attribute__((ext_vector_type(8))) short s16x8;

__device__ __forceinline__ unsigned short f2bf(float f) {
  union { float f; uint32_t u; } v; v.f = f;
  uint32_t u = v.u;
  u += 0x7fffu + ((u >> 16) & 1u);   // RNE
  return (unsigned short)(u >> 16);
}
__device__ __forceinline__ float bf2f(unsigned short h) {
  union { uint32_t u; float f; } v; v.u = ((uint32_t)h) << 16;
  return v.f;
}

// src [N][K] fp32 -> dst [N][3K] bf16 as [hi | lo | hi] K-blocks. K = 1<<kshift.
__global__ void k_split(const float* __restrict__ src, uint16_t* __restrict__ dst,
                        int kshift, int total) {
  int K = 1 << kshift;
  for (int i = blockIdx.x * blockDim.x + threadIdx.x; i < total;
       i += gridDim.x * blockDim.x) {
    int n = i >> kshift, k = i & (K - 1);
    float f = src[i];
    unsigned short hi = f2bf(f);
    unsigned short lo = f2bf(f - bf2f(hi));
    size_t base = (size_t)n * (3 * K);
    dst[base + k] = hi;
    dst[base + K + k] = lo;
    dst[base + 2 * K + k] = hi;
  }
}

__global__ void k_init(const float* __restrict__ h0, float* __restrict__ h,
                       uint16_t* __restrict__ h2) {
  for (int i = blockIdx.x * blockDim.x + threadIdx.x; i < B_ * H_;
       i += gridDim.x * blockDim.x) {
    float f = h0[i];
    h[i] = f;
    int b = i >> 10, j = i & 1023;
    unsigned short hi = f2bf(f);
    h2[b * 2048 + j] = hi;
    h2[b * 2048 + 1024 + j] = f2bf(f - bf2f(hi));
  }
}

// Projection GEMM (unchanged from round 1): XP[tt][gate][b][j] = x@W^T + bias
__global__ __launch_bounds__(256) void k_proj(
    const float* __restrict__ x, const uint16_t* __restrict__ W2,
    const float* __restrict__ bz, const float* __restrict__ br,
    const float* __restrict__ bh,
    float* __restrict__ XP, int t0, int Tc, int MT) {
  __shared__ uint16_t As[128][72];
  __shared__ uint16_t Bs[128][72];
  int bid = blockIdx.x;
  int mt = bid % MT, nt = bid / MT;
  int tid = threadIdx.x;
  int w = tid >> 6, l = tid & 63;
  int wm = w >> 1, wn = w & 1;
  int lr = l & 15, lg = l >> 4;

  int gr[4], gc8[4];
  const float* asrc[4];
  const uint16_t* bsrc[4];
#pragma unroll
  for (int g = 0; g < 4; ++g) {
    int gran = tid + 256 * g;
    int r = gran >> 3, c8 = gran & 7;
    gr[g] = r; gc8[g] = c8;
    int n = mt * 128 + r;
    int b = n / Tc, tt = n % Tc;
    asrc[g] = x + ((size_t)b * T_ + (t0 + tt)) * I_;
    bsrc[g] = W2 + (size_t)(nt * 128 + r) * 1536;
  }

  f32x4 acc[4][4];
#pragma unroll
  for (int mi = 0; mi < 4; ++mi)
#pragma unroll
    for (int ni = 0; ni < 4; ++ni) {
      acc[mi][ni][0] = 0.f; acc[mi][ni][1] = 0.f;
      acc[mi][ni][2] = 0.f; acc[mi][ni][3] = 0.f;
    }

  float4 pa[8];
  uint4 pb[4];
#pragma unroll
  for (int g = 0; g < 4; ++g) {
    int kp = gc8[g] * 8;
    int xc = kp & 511;
    pa[2 * g] = *(const float4*)(asrc[g] + xc);
    pa[2 * g + 1] = *(const float4*)(asrc[g] + xc + 4);
    pb[g] = *(const uint4*)(bsrc[g] + kp);
  }

  for (int it = 0; it < 24; ++it) {
    __syncthreads();
    {
      int k0 = it * 64;
#pragma unroll
      for (int g = 0; g < 4; ++g) {
        int kp = k0 + gc8[g] * 8;
        bool lofl = (kp >= 1024);
        const float* pf = (const float*)&pa[2 * g];
        s16x8 v;
#pragma unroll
        for (int j = 0; j < 8; ++j) {
          float f = pf[j];
          unsigned short hi = f2bf(f);
          v[j] = (short)(lofl ? f2bf(f - bf2f(hi)) : hi);
        }
        *(s16x8*)(&As[gr[g]][gc8[g] * 8]) = v;
        *(uint4*)(&Bs[gr[g]][gc8[g] * 8]) = pb[g];
      }
    }
    if (it + 1 < 24) {
      int k0 = (it + 1) * 64;
#pragma unroll
      for (int g = 0; g < 4; ++g) {
        int kp = k0 + gc8[g] * 8;
        int xc = kp & 511;
        pa[2 * g] = *(const float4*)(asrc[g] + xc);
        pa[2 * g + 1] = *(const float4*)(asrc[g] + xc + 4);
        pb[g] = *(const uint4*)(bsrc[g] + kp);
      }
    }
    __syncthreads();
#pragma unroll
    for (int kk = 0; kk < 64; kk += 32) {
      s16x8 af[4], bf[4];
#pragma unroll
      for (int mi = 0; mi < 4; ++mi)
        af[mi] = *(const s16x8*)(&As[wm * 64 + mi * 16 + lr][kk + lg * 8]);
#pragma unroll
      for (int ni = 0; ni < 4; ++ni)
        bf[ni] = *(const s16x8*)(&Bs[wn * 64 + ni * 16 + lr][kk + lg * 8]);
#pragma unroll
      for (int mi = 0; mi < 4; ++mi)
#pragma unroll
        for (int ni = 0; ni < 4; ++ni)
          acc[mi][ni] = __builtin_amdgcn_mfma_f32_16x16x32_bf16(
              af[mi], bf[ni], acc[mi][ni], 0, 0, 0);
    }
  }

  int g_ = (nt * 128) >> 10;
  const float* bias = (g_ == 0) ? bz : ((g_ == 1) ? br : bh);
#pragma unroll
  for (int ni = 0; ni < 4; ++ni) {
    int col = nt * 128 + wn * 64 + ni * 16 + lr;
    int jc = col & 1023;
    float bv = bias[jc];
#pragma unroll
    for (int mi = 0; mi < 4; ++mi) {
      int nrow = mt * 128 + wm * 64 + mi * 16 + lg * 4;
      int b = nrow / Tc, tt = nrow % Tc;
#pragma unroll
      for (int v = 0; v < 4; ++v) {
        XP[((size_t)((tt * 3 + g_) * 64 + b)) * 1024 + jc] = acc[mi][ni][v] + bv;
        if (++tt == Tc) { tt = 0; ++b; }
      }
    }
  }
}

// ---- tree grid barrier: buckets -> root -> gen. Agent-scope, L2-bypassing. ----
__device__ __forceinline__ void gridbar(unsigned* bar) {
  __syncthreads();
  if (threadIdx.x == 0) {
    unsigned* gen = bar + 544;
    unsigned g = __hip_atomic_load(gen, __ATOMIC_RELAXED, __HIP_MEMORY_SCOPE_AGENT);
    __threadfence();   // release: flush this XCD's L2 (our phase writes)
    unsigned* bucket = bar + (blockIdx.x & (NBUCK - 1)) * 32;
    unsigned old = __hip_atomic_fetch_add(bucket, 1u, __ATOMIC_RELAXED,
                                          __HIP_MEMORY_SCOPE_AGENT);
    if (old == BUCK_SZ - 1) {
      __hip_atomic_store(bucket, 0u, __ATOMIC_RELAXED, __HIP_MEMORY_SCOPE_AGENT);
      unsigned rold = __hip_atomic_fetch_add(bar + 512, 1u, __ATOMIC_RELAXED,
                                             __HIP_MEMORY_SCOPE_AGENT);
      if (rold == NBUCK - 1) {
        __hip_atomic_store(bar + 512, 0u, __ATOMIC_RELAXED, __HIP_MEMORY_SCOPE_AGENT);
        __hip_atomic_fetch_add(gen, 1u, __ATOMIC_RELAXED, __HIP_MEMORY_SCOPE_AGENT);
      }
    }
    while (__hip_atomic_load(gen, __ATOMIC_RELAXED, __HIP_MEMORY_SCOPE_AGENT) == g)
      __builtin_amdgcn_s_sleep(2);
    __threadfence();   // acquire: invalidate L2 so we see other XCDs' writes
  }
  __syncthreads();
}

// ---- persistent recurrence kernel ----
// wgs 0..127: phase A (ZR cols, 16 each of 2048). wgs 128..191: phase B (HT cols).
// LDS: 16 rows x 3072 k' bf16 [hi|lo|hi], XOR-swizzled (2-way banks) = 96 KB
//      + red[8][64][17] = 34 KB.
__global__ __launch_bounds__(512) void k_recur(
    const float* __restrict__ Uz, const float* __restrict__ Ur,
    const float* __restrict__ Uh, const float* __restrict__ XP,
    int t0, int Tcc, float* __restrict__ h, uint16_t* __restrict__ h2,
    uint16_t* __restrict__ s2, float* __restrict__ zbuf,
    float* __restrict__ out, unsigned* __restrict__ bar) {
  __shared__ uint16_t Wl[16 * 3072];
  __shared__ float red[8 * 64 * 17];

  const int tid = threadIdx.x;
  const int w = tid >> 6, l = tid & 63;
  const int lr = l & 15, lg = l >> 4;
  const int bid = blockIdx.x;
  const bool isA = (bid < NWG_A);
  const int tile = isA ? bid : (bid - NWG_A);
  const int n0 = tile * 16;

  // stage weights fp32 -> [hi|lo|hi] bf16 into swizzled LDS (once)
  const float* src = isA ? ((n0 < 1024) ? (Uz + (size_t)n0 * 1024)
                                        : (Ur + (size_t)(n0 - 1024) * 1024))
                         : (Uh + (size_t)n0 * 1024);
  for (int i = tid; i < 2048; i += 512) {
    int r = i >> 7;
    int k8 = (i & 127) * 8;
    const float* p = src + r * 1024 + k8;
    s16x8 hi8, lo8;
#pragma unroll
    for (int j = 0; j < 8; ++j) {
      float f = p[j];
      unsigned short hb = f2bf(f);
      hi8[j] = (short)hb;
      lo8[j] = (short)f2bf(f - bf2f(hb));
    }
    uint8_t* rowp = (uint8_t*)Wl + r * 6144;
    int swz = (r & 7) << 4;
    *(s16x8*)(rowp + ((k8 * 2) ^ swz)) = hi8;
    *(s16x8*)(rowp + (((1024 + k8) * 2) ^ swz)) = lo8;
    *(s16x8*)(rowp + (((2048 + k8) * 2) ^ swz)) = hi8;
  }
  __syncthreads();

  const int KB0 = w * 128;          // this wave's 128-wide k' slice per segment
  const int bswz = (lr & 7) << 4;
  const uint8_t* browp = (const uint8_t*)Wl + lr * 6144;

  for (int tt = 0; tt < Tcc; ++tt) {
    const int t = t0 + tt;
    float xpre[2], hpre[2];
    if (isA) {
      // prefetch epilogue inputs (h is stable during phase A)
#pragma unroll
      for (int u = 0; u < 2; ++u) {
        int e = tid + u * 512;
        int b = e >> 4, c = e & 15;
        int n = n0 + c;
        if (n < 1024) {
          xpre[u] = XP[((size_t)(tt * 3 + 0) * 64 + b) * 1024 + n];
          hpre[u] = 0.f;
        } else {
          xpre[u] = XP[((size_t)(tt * 3 + 1) * 64 + b) * 1024 + (n - 1024)];
          hpre[u] = h[b * 1024 + (n - 1024)];
        }
      }
      f32x4 acc[4];
#pragma unroll
      for (int mi = 0; mi < 4; ++mi) {
        acc[mi][0] = 0.f; acc[mi][1] = 0.f; acc[mi][2] = 0.f; acc[mi][3] = 0.f;
      }
      s16x8 ah[4][4];
#pragma unroll
      for (int ks = 0; ks < 4; ++ks) {   // seg0: A_hi * B_hi
        int kp = KB0 + ks * 32 + lg * 8;
        s16x8 bfv = *(const s16x8*)(browp + ((kp * 2) ^ bswz));
#pragma unroll
        for (int mi = 0; mi < 4; ++mi) {
          ah[ks][mi] = *(const s16x8*)(h2 + (size_t)(lr + 16 * mi) * 2048 + kp);
          acc[mi] = __builtin_amdgcn_mfma_f32_16x16x32_bf16(ah[ks][mi], bfv,
                                                            acc[mi], 0, 0, 0);
        }
      }
#pragma unroll
      for (int ks = 0; ks < 4; ++ks) {   // seg1: A_hi (reused) * B_lo
        int kp = 1024 + KB0 + ks * 32 + lg * 8;
        s16x8 bfv = *(const s16x8*)(browp + ((kp * 2) ^ bswz));
#pragma unroll
        for (int mi = 0; mi < 4; ++mi)
          acc[mi] = __builtin_amdgcn_mfma_f32_16x16x32_bf16(ah[ks][mi], bfv,
                                                            acc[mi], 0, 0, 0);
      }
#pragma unroll
      for (int ks = 0; ks < 4; ++ks) {   // seg2: A_lo * B_hi
        int kp = 2048 + KB0 + ks * 32 + lg * 8;
        int ac = kp - 1024;
        s16x8 bfv = *(const s16x8*)(browp + ((kp * 2) ^ bswz));
#pragma unroll
        for (int mi = 0; mi < 4; ++mi) {
          s16x8 af = *(const s16x8*)(h2 + (size_t)(lr + 16 * mi) * 2048 + ac);
          acc[mi] = __builtin_amdgcn_mfma_f32_16x16x32_bf16(af, bfv,
                                                            acc[mi], 0, 0, 0);
        }
      }
#pragma unroll
      for (int mi = 0; mi < 4; ++mi)
#pragma unroll
        for (int v = 0; v < 4; ++v)
          red[(w * 64 + mi * 16 + lg * 4 + v) * 17 + lr] = acc[mi][v];
      __syncthreads();
#pragma unroll
      for (int u = 0; u < 2; ++u) {
        int e = tid + u * 512;
        int b = e >> 4, c = e & 15;
        float s = 0.f;
#pragma unroll
        for (int q = 0; q < 8; ++q) s += red[(q * 64 + b) * 17 + c];
        int n = n0 + c;
        if (n < 1024) {
          float pre = s + xpre[u];
          zbuf[b * 1024 + n] = 1.f / (1.f + __expf(-pre));
        } else {
          int j = n - 1024;
          float pre = s + xpre[u];
          float r = 1.f / (1.f + __expf(-pre));
          float sv = r * hpre[u];
          unsigned short hb = f2bf(sv);
          s2[b * 2048 + j] = hb;
          s2[b * 2048 + 1024 + j] = f2bf(sv - bf2f(hb));
        }
      }
    } else {
      // group B: prefetch its epilogue inputs during phase A
#pragma unroll
      for (int u = 0; u < 2; ++u) {
        int e = tid + u * 512;
        int b = e >> 4, c = e & 15;
        int j = n0 + c;
        xpre[u] = XP[((size_t)(tt * 3 + 2) * 64 + b) * 1024 + j];
        hpre[u] = h[b * 1024 + j];
      }
    }
    gridbar(bar);
    if (!isA) {
      f32x4 acc[4];
#pragma unroll
      for (int mi = 0; mi < 4; ++mi) {
        acc[mi][0] = 0.f; acc[mi][1] = 0.f; acc[mi][2] = 0.f; acc[mi][3] = 0.f;
      }
      s16x8 ah[4][4];
#pragma unroll
      for (int ks = 0; ks < 4; ++ks) {
        int kp = KB0 + ks * 32 + lg * 8;
        s16x8 bfv = *(const s16x8*)(browp + ((kp * 2) ^ bswz));
#pragma unroll
        for (int mi = 0; mi < 4; ++mi) {
          ah[ks][mi] = *(const s16x8*)(s2 + (size_t)(lr + 16 * mi) * 2048 + kp);
          acc[mi] = __builtin_amdgcn_mfma_f32_16x16x32_bf16(ah[ks][mi], bfv,
                                                            acc[mi], 0, 0, 0);
        }
      }
#pragma unroll
      for (int ks = 0; ks < 4; ++ks) {
        int kp = 1024 + KB0 + ks * 32 + lg * 8;
        s16x8 bfv = *(const s16x8*)(browp + ((kp * 2) ^ bswz));
#pragma unroll
        for (int mi = 0; mi < 4; ++mi)
          acc[mi] = __builtin_amdgcn_mfma_f32_16x16x32_bf16(ah[ks][mi], bfv,
                                                            acc[mi], 0, 0, 0);
      }
#pragma unroll
      for (int ks = 0; ks < 4; ++ks) {
        int kp = 2048 + KB0 + ks * 32 + lg * 8;
        int ac = kp - 1024;
        s16x8 bfv = *(const s16x8*)(browp + ((kp * 2) ^ bswz));
#pragma unroll
        for (int mi = 0; mi < 4; ++mi) {
          s16x8 af = *(const s16x8*)(s2 + (size_t)(lr + 16 * mi) * 2048 + ac);
          acc[mi] = __builtin_amdgcn_mfma_f32_16x16x32_bf16(af, bfv,
                                                            acc[mi], 0, 0, 0);
        }
      }
#pragma unroll
      for (int mi = 0; mi < 4; ++mi)
#pragma unroll
        for (int v = 0; v < 4; ++v)
          red[(w * 64 + mi * 16 + lg * 4 + v) * 17 + lr] = acc[mi][v];
      __syncthreads();
#pragma unroll
      for (int u = 0; u < 2; ++u) {
        int e = tid + u * 512;
        int b = e >> 4, c = e & 15;
        float s = 0.f;
#pragma unroll
        for (int q = 0; q < 8; ++q) s += red[(q * 64 + b) * 17 + c];
        int j = n0 + c;
        float pre = s + xpre[u];
        float ht = tanhf(pre);
        float z = zbuf[b * 1024 + j];
        float hv = hpre[u];
        float hn = (1.f - z) * hv + z * ht;
        h[b * 1024 + j] = hn;
        unsigned short hb = f2bf(hn);
        h2[b * 2048 + j] = hb;
        h2[b * 2048 + 1024 + j] = f2bf(hn - bf2f(hb));
        out[((size_t)b * T_ + t) * 1024 + j] = hn;
        if (t == T_ - 1) out[(size_t)B_ * T_ * 1024 + b * 1024 + j] = hn;
      }
    }
    gridbar(bar);
  }
}

extern "C" void kernel_launch(void* const* d_in, const int* in_sizes, int n_in,
                              void* d_out, int out_size, void* d_ws, size_t ws_size,
                              hipStream_t stream) {
  const float* x  = (const float*)d_in[0];
  const float* h0 = (const float*)d_in[1];
  const float* Wz = (const float*)d_in[2];
  const float* bz = (const float*)d_in[3];
  const float* Uz = (const float*)d_in[4];
  const float* Wr = (const float*)d_in[5];
  const float* br = (const float*)d_in[6];
  const float* Ur = (const float*)d_in[7];
  const float* Wh = (const float*)d_in[8];
  const float* bh = (const float*)d_in[9];
  const float* Uh = (const float*)d_in[10];
  float* out = (float*)d_out;

  uint8_t* ws = (uint8_t*)d_ws;
  uint16_t* W2   = (uint16_t*)(ws + 0);          // [3072][1536] bf16
  float*    hbuf = (float*)   (ws + 9437184);    // [64][1024]
  uint16_t* h2   = (uint16_t*)(ws + 9699328);    // [64][2048]
  uint16_t* s2   = (uint16_t*)(ws + 9961472);    // [64][2048]
  float*    zbuf = (float*)   (ws + 10223616);   // [64][1024]
  unsigned* bar  = (unsigned*)(ws + 10485760);   // 4 KB barrier state
  float*    XP   = (float*)   (ws + 10489856);   // [Tc][3][64][1024] fp32

  hipMemsetAsync(bar, 0, 4096, stream);

  k_split<<<512, 256, 0, stream>>>(Wz, W2, 9, 1024 * 512);
  k_split<<<512, 256, 0, stream>>>(Wr, W2 + (size_t)1024 * 1536, 9, 1024 * 512);
  k_split<<<512, 256, 0, stream>>>(Wh, W2 + (size_t)2048 * 1536, 9, 1024 * 512);
  k_init<<<64, 256, 0, stream>>>(h0, hbuf, h2);

  size_t avail = (ws_size > 10489856u) ? (ws_size - 10489856u) : 0u;
  long long tcl = (long long)(avail / 786432u);
  int Tc = (tcl > 512) ? 512 : (int)tcl;
  Tc &= ~1;
  if (Tc < 2) Tc = 2;

  for (int t0 = 0; t0 < T_; t0 += Tc) {
    int Tcc = (Tc < T_ - t0) ? Tc : (T_ - t0);
    int MT = (B_ * Tcc) / 128;
    k_proj<<<MT * 24, 256, 0, stream>>>(x, W2, bz, br, bh, XP, t0, Tcc, MT);

    int t0v = t0, tccv = Tcc;
    void* args[] = {(void*)&Uz, (void*)&Ur, (void*)&Uh, (void*)&XP,
                    (void*)&t0v, (void*)&tccv, (void*)&hbuf, (void*)&h2,
                    (void*)&s2, (void*)&zbuf, (void*)&out, (void*)&bar};
    hipLaunchCooperativeKernel((void*)k_recur, dim3(NWG), dim3(512),
                               args, 0, stream);
  }
}

// Round 3
// 17379.469 us; speedup vs baseline: 1.1506x; 1.1506x over previous
//
#include <hip/hip_runtime.h>
#include <hip/hip_bf16.h>
#include <stdint.h>

// GRU B=64 T=512 I=512 H=1024, fp32 in/out.
// bf16 hi/lo 3-pass MFMA numerics (identical to rounds 1-2).
// Round 3: persistent kernel with FENCE-FREE cross-XCD handoff:
//   - cross-phase data via write-through (sc0 sc1) stores + cache-bypass loads
//   - per-producer generation flags, wave-parallel polling (no atomics, no
//     threadfence, no buffer_wbl2/buffer_inv)
//   - B-wgs keep their h slice in registers across all steps

#define B_ 64
#define T_ 512
#define I_ 512
#define H_ 1024
#define NWG_A 128
#define NWG_B 64
#define NWG 192

typedef __attribute__((ext_vector_type(4))) float f32x4;
typedef __attribute__((ext_vector_type(8))) short s16x8;
typedef __attribute__((ext_vector_type(2))) unsigned int u32x2;

__device__ __forceinline__ unsigned short f2bf(float f) {
  union { float f; uint32_t u; } v; v.f = f;
  uint32_t u = v.u;
  u += 0x7fffu + ((u >> 16) & 1u);   // RNE
  return (unsigned short)(u >> 16);
}
__device__ __forceinline__ float bf2f(unsigned short h) {
  union { uint32_t u; float f; } v; v.u = ((uint32_t)h) << 16;
  return v.f;
}

// ---- coherent (sc0 sc1) memory helpers: bypass L1/L2, serialize at L3 ----
__device__ __forceinline__ s16x8 sc_load_b128(const uint16_t* p) {
  s16x8 r;
  asm volatile("global_load_dwordx4 %0, %1, off sc0 sc1"
               : "=v"(r) : "v"(p) : "memory");
  return r;
}
__device__ __forceinline__ float sc_load_f32(const float* p) {
  float r;
  asm volatile("global_load_dword %0, %1, off sc0 sc1"
               : "=v"(r) : "v"(p) : "memory");
  return r;
}
__device__ __forceinline__ void sc_store_f32(float* p, float v) {
  asm volatile("global_store_dword %0, %1, off sc0 sc1"
               :: "v"(p), "v"(v) : "memory");
}
__device__ __forceinline__ void sc_store_u16(uint16_t* p, unsigned v) {
  asm volatile("global_store_short %0, %1, off sc0 sc1"
               :: "v"(p), "v"(v) : "memory");
}
__device__ __forceinline__ void sc_store_u32(unsigned* p, unsigned v) {
  asm volatile("global_store_dword %0, %1, off sc0 sc1"
               :: "v"(p), "v"(v) : "memory");
}
__device__ __forceinline__ void vm_drain() {
  asm volatile("s_waitcnt vmcnt(0)" ::: "memory");
}

// src [N][K] fp32 -> dst [N][3K] bf16 as [hi | lo | hi] K-blocks. K = 1<<kshift.
__global__ void k_split(const float* __restrict__ src, uint16_t* __restrict__ dst,
                        int kshift, int total) {
  int K = 1 << kshift;
  for (int i = blockIdx.x * blockDim.x + threadIdx.x; i < total;
       i += gridDim.x * blockDim.x) {
    int n = i >> kshift, k = i & (K - 1);
    float f = src[i];
    unsigned short hi = f2bf(f);
    unsigned short lo = f2bf(f - bf2f(hi));
    size_t base = (size_t)n * (3 * K);
    dst[base + k] = hi;
    dst[base + K + k] = lo;
    dst[base + 2 * K + k] = hi;
  }
}

__global__ void k_init(const float* __restrict__ h0, float* __restrict__ h,
                       uint16_t* __restrict__ h2) {
  for (int i = blockIdx.x * blockDim.x + threadIdx.x; i < B_ * H_;
       i += gridDim.x * blockDim.x) {
    float f = h0[i];
    h[i] = f;
    int b = i >> 10, j = i & 1023;
    unsigned short hi = f2bf(f);
    h2[b * 2048 + j] = hi;
    h2[b * 2048 + 1024 + j] = f2bf(f - bf2f(hi));
  }
}

// Projection GEMM (unchanged): XP[tt][gate][b][j] = x@W^T + bias
__global__ __launch_bounds__(256) void k_proj(
    const float* __restrict__ x, const uint16_t* __restrict__ W2,
    const float* __restrict__ bz, const float* __restrict__ br,
    const float* __restrict__ bh,
    float* __restrict__ XP, int t0, int Tc, int MT) {
  __shared__ uint16_t As[128][72];
  __shared__ uint16_t Bs[128][72];
  int bid = blockIdx.x;
  int mt = bid % MT, nt = bid / MT;
  int tid = threadIdx.x;
  int w = tid >> 6, l = tid & 63;
  int wm = w >> 1, wn = w & 1;
  int lr = l & 15, lg = l >> 4;

  int gr[4], gc8[4];
  const float* asrc[4];
  const uint16_t* bsrc[4];
#pragma unroll
  for (int g = 0; g < 4; ++g) {
    int gran = tid + 256 * g;
    int r = gran >> 3, c8 = gran & 7;
    gr[g] = r; gc8[g] = c8;
    int n = mt * 128 + r;
    int b = n / Tc, tt = n % Tc;
    asrc[g] = x + ((size_t)b * T_ + (t0 + tt)) * I_;
    bsrc[g] = W2 + (size_t)(nt * 128 + r) * 1536;
  }

  f32x4 acc[4][4];
#pragma unroll
  for (int mi = 0; mi < 4; ++mi)
#pragma unroll
    for (int ni = 0; ni < 4; ++ni) {
      acc[mi][ni][0] = 0.f; acc[mi][ni][1] = 0.f;
      acc[mi][ni][2] = 0.f; acc[mi][ni][3] = 0.f;
    }

  float4 pa[8];
  uint4 pb[4];
#pragma unroll
  for (int g = 0; g < 4; ++g) {
    int kp = gc8[g] * 8;
    int xc = kp & 511;
    pa[2 * g] = *(const float4*)(asrc[g] + xc);
    pa[2 * g + 1] = *(const float4*)(asrc[g] + xc + 4);
    pb[g] = *(const uint4*)(bsrc[g] + kp);
  }

  for (int it = 0; it < 24; ++it) {
    __syncthreads();
    {
      int k0 = it * 64;
#pragma unroll
      for (int g = 0; g < 4; ++g) {
        int kp = k0 + gc8[g] * 8;
        bool lofl = (kp >= 1024);
        const float* pf = (const float*)&pa[2 * g];
        s16x8 v;
#pragma unroll
        for (int j = 0; j < 8; ++j) {
          float f = pf[j];
          unsigned short hi = f2bf(f);
          v[j] = (short)(lofl ? f2bf(f - bf2f(hi)) : hi);
        }
        *(s16x8*)(&As[gr[g]][gc8[g] * 8]) = v;
        *(uint4*)(&Bs[gr[g]][gc8[g] * 8]) = pb[g];
      }
    }
    if (it + 1 < 24) {
      int k0 = (it + 1) * 64;
#pragma unroll
      for (int g = 0; g < 4; ++g) {
        int kp = k0 + gc8[g] * 8;
        int xc = kp & 511;
        pa[2 * g] = *(const float4*)(asrc[g] + xc);
        pa[2 * g + 1] = *(const float4*)(asrc[g] + xc + 4);
        pb[g] = *(const uint4*)(bsrc[g] + kp);
      }
    }
    __syncthreads();
#pragma unroll
    for (int kk = 0; kk < 64; kk += 32) {
      s16x8 af[4], bf[4];
#pragma unroll
      for (int mi = 0; mi < 4; ++mi)
        af[mi] = *(const s16x8*)(&As[wm * 64 + mi * 16 + lr][kk + lg * 8]);
#pragma unroll
      for (int ni = 0; ni < 4; ++ni)
        bf[ni] = *(const s16x8*)(&Bs[wn * 64 + ni * 16 + lr][kk + lg * 8]);
#pragma unroll
      for (int mi = 0; mi < 4; ++mi)
#pragma unroll
        for (int ni = 0; ni < 4; ++ni)
          acc[mi][ni] = __builtin_amdgcn_mfma_f32_16x16x32_bf16(
              af[mi], bf[ni], acc[mi][ni], 0, 0, 0);
    }
  }

  int g_ = (nt * 128) >> 10;
  const float* bias = (g_ == 0) ? bz : ((g_ == 1) ? br : bh);
#pragma unroll
  for (int ni = 0; ni < 4; ++ni) {
    int col = nt * 128 + wn * 64 + ni * 16 + lr;
    int jc = col & 1023;
    float bv = bias[jc];
#pragma unroll
    for (int mi = 0; mi < 4; ++mi) {
      int nrow = mt * 128 + wm * 64 + mi * 16 + lg * 4;
      int b = nrow / Tc, tt = nrow % Tc;
#pragma unroll
      for (int v = 0; v < 4; ++v) {
        XP[((size_t)((tt * 3 + g_) * 64 + b)) * 1024 + jc] = acc[mi][ni][v] + bv;
        if (++tt == Tc) { tt = 0; ++b; }
      }
    }
  }
}

// ---- persistent recurrence kernel ----
// wgs 0..63:   phase A, z columns (n0 = bid*16 < 1024)
// wgs 64..127: phase A, r columns (n0-1024 = h column slice), produce s2
// wgs 128..191: phase B, h~ columns, keep h slice in registers
// Flags: flagsA[128], flagsB[64] hold # completed phases (monotonic, no reset).
__global__ __launch_bounds__(512) void k_recur(
    const float* __restrict__ Uz, const float* __restrict__ Ur,
    const float* __restrict__ Uh, const float* __restrict__ XP,
    int t0i, int Tcc, float* __restrict__ h, uint16_t* __restrict__ h2,
    uint16_t* __restrict__ s2, float* __restrict__ zbuf,
    float* __restrict__ out, unsigned* __restrict__ flagsA,
    unsigned* __restrict__ flagsB) {
  __shared__ uint16_t Wl[16 * 3072];
  __shared__ float red[8 * 64 * 17];

  const int tid = threadIdx.x;
  const int w = tid >> 6, l = tid & 63;
  const int lr = l & 15, lg = l >> 4;
  const int bid = blockIdx.x;
  const bool isA = (bid < NWG_A);
  const int tile = isA ? bid : (bid - NWG_A);
  const int n0 = tile * 16;
  const bool isR = isA && (n0 >= 1024);   // whole wg uniform

  // stage weights fp32 -> [hi|lo|hi] bf16 into swizzled LDS (once)
  const float* src = isA ? ((n0 < 1024) ? (Uz + (size_t)n0 * 1024)
                                        : (Ur + (size_t)(n0 - 1024) * 1024))
                         : (Uh + (size_t)n0 * 1024);
  for (int i = tid; i < 2048; i += 512) {
    int r = i >> 7;
    int k8 = (i & 127) * 8;
    const float* p = src + r * 1024 + k8;
    s16x8 hi8, lo8;
#pragma unroll
    for (int j = 0; j < 8; ++j) {
      float f = p[j];
      unsigned short hb = f2bf(f);
      hi8[j] = (short)hb;
      lo8[j] = (short)f2bf(f - bf2f(hb));
    }
    uint8_t* rowp = (uint8_t*)Wl + r * 6144;
    int swz = (r & 7) << 4;
    *(s16x8*)(rowp + ((k8 * 2) ^ swz)) = hi8;
    *(s16x8*)(rowp + (((1024 + k8) * 2) ^ swz)) = lo8;
    *(s16x8*)(rowp + (((2048 + k8) * 2) ^ swz)) = hi8;
  }
  __syncthreads();

  const int KB0 = w * 128;
  const int bswz = (lr & 7) << 4;
  const uint8_t* browp = (const uint8_t*)Wl + lr * 6144;

  // epilogue thread mapping (each thread owns 2 of the wg's 1024 outputs)
  int eb[2], ec[2];
#pragma unroll
  for (int u = 0; u < 2; ++u) {
    int e = tid + u * 512;
    eb[u] = e >> 4; ec[u] = e & 15;
  }

  // B-wgs: h slice lives in registers for the whole kernel
  float hreg[2];
  if (!isA) {
#pragma unroll
    for (int u = 0; u < 2; ++u)
      hreg[u] = h[eb[u] * 1024 + (n0 + ec[u])];   // launch-start inv => safe
  }

  for (int tt = 0; tt < Tcc; ++tt) {
    const unsigned t = (unsigned)(t0i + tt);

    // prefetch XP slice (plain cached loads; XP immutable this launch)
    float xpre[2];
    {
      int gate = isA ? (isR ? 1 : 0) : 2;
#pragma unroll
      for (int u = 0; u < 2; ++u) {
        int jc = (n0 + ec[u]) & 1023;
        xpre[u] = XP[((size_t)(tt * 3 + gate) * 64 + eb[u]) * 1024 + jc];
      }
    }

    if (isA) {
      // wait for phase B of step t-1 (h2 ready)
      if (t > 0 && w == 0) {
        const unsigned* fp = flagsB + l;
        for (;;) {
          unsigned f;
          asm volatile("global_load_dword %0, %1, off sc0 sc1\n\t"
                       "s_waitcnt vmcnt(0)"
                       : "=v"(f) : "v"(fp) : "memory");
          if (__all(f >= t)) break;
        }
      }
      __syncthreads();

      // r-wgs need h (for s = r*h) — sc load after the poll
      float hpre[2];
      if (isR) {
#pragma unroll
        for (int u = 0; u < 2; ++u)
          hpre[u] = sc_load_f32(h + eb[u] * 1024 + (n0 - 1024 + ec[u]));
      }

      // issue all A-fragment loads (hi then lo), 32 outstanding
      s16x8 ah[4][4], al[4][4];
#pragma unroll
      for (int ks = 0; ks < 4; ++ks)
#pragma unroll
        for (int mi = 0; mi < 4; ++mi)
          ah[ks][mi] = sc_load_b128(h2 + (size_t)(lr + 16 * mi) * 2048 +
                                    (KB0 + ks * 32 + lg * 8));
#pragma unroll
      for (int ks = 0; ks < 4; ++ks)
#pragma unroll
        for (int mi = 0; mi < 4; ++mi)
          al[ks][mi] = sc_load_b128(h2 + (size_t)(lr + 16 * mi) * 2048 +
                                    (1024 + KB0 + ks * 32 + lg * 8));

      f32x4 acc[4];
#pragma unroll
      for (int mi = 0; mi < 4; ++mi) {
        acc[mi][0] = 0.f; acc[mi][1] = 0.f; acc[mi][2] = 0.f; acc[mi][3] = 0.f;
      }

      asm volatile("s_waitcnt vmcnt(16)" ::: "memory");
      __builtin_amdgcn_sched_barrier(0);
#pragma unroll
      for (int ks = 0; ks < 4; ++ks) {   // seg0: A_hi * B_hi
        int kp = KB0 + ks * 32 + lg * 8;
        s16x8 bfv = *(const s16x8*)(browp + ((kp * 2) ^ bswz));
#pragma unroll
        for (int mi = 0; mi < 4; ++mi)
          acc[mi] = __builtin_amdgcn_mfma_f32_16x16x32_bf16(ah[ks][mi], bfv,
                                                            acc[mi], 0, 0, 0);
      }
#pragma unroll
      for (int ks = 0; ks < 4; ++ks) {   // seg1: A_hi * B_lo
        int kp = 1024 + KB0 + ks * 32 + lg * 8;
        s16x8 bfv = *(const s16x8*)(browp + ((kp * 2) ^ bswz));
#pragma unroll
        for (int mi = 0; mi < 4; ++mi)
          acc[mi] = __builtin_amdgcn_mfma_f32_16x16x32_bf16(ah[ks][mi], bfv,
                                                            acc[mi], 0, 0, 0);
      }
      vm_drain();
      __builtin_amdgcn_sched_barrier(0);
#pragma unroll
      for (int ks = 0; ks < 4; ++ks) {   // seg2: A_lo * B_hi
        int kp = 2048 + KB0 + ks * 32 + lg * 8;
        s16x8 bfv = *(const s16x8*)(browp + ((kp * 2) ^ bswz));
#pragma unroll
        for (int mi = 0; mi < 4; ++mi)
          acc[mi] = __builtin_amdgcn_mfma_f32_16x16x32_bf16(al[ks][mi], bfv,
                                                            acc[mi], 0, 0, 0);
      }
#pragma unroll
      for (int mi = 0; mi < 4; ++mi)
#pragma unroll
        for (int v = 0; v < 4; ++v)
          red[(w * 64 + mi * 16 + lg * 4 + v) * 17 + lr] = acc[mi][v];
      __syncthreads();

#pragma unroll
      for (int u = 0; u < 2; ++u) {
        int b = eb[u], c = ec[u];
        float s = 0.f;
#pragma unroll
        for (int q = 0; q < 8; ++q) s += red[(q * 64 + b) * 17 + c];
        float pre = s + xpre[u];
        if (!isR) {
          int n = n0 + c;
          sc_store_f32(zbuf + b * 1024 + n, 1.f / (1.f + __expf(-pre)));
        } else {
          int j = n0 - 1024 + c;
          float r = 1.f / (1.f + __expf(-pre));
          float sv = r * hpre[u];
          unsigned short hb = f2bf(sv);
          sc_store_u16(s2 + b * 2048 + j, hb);
          sc_store_u16(s2 + b * 2048 + 1024 + j, f2bf(sv - bf2f(hb)));
        }
      }
      vm_drain();
      __syncthreads();
      if (tid == 0) sc_store_u32(flagsA + tile, t + 1);
    } else {
      // ---- phase B ----
      if (w == 0) {   // wait for ALL of phase A of step t
        const u32x2* fp = (const u32x2*)flagsA + l;
        unsigned tgt = t + 1;
        for (;;) {
          u32x2 f;
          asm volatile("global_load_dwordx2 %0, %1, off sc0 sc1\n\t"
                       "s_waitcnt vmcnt(0)"
                       : "=v"(f) : "v"(fp) : "memory");
          if (__all((f.x >= tgt) && (f.y >= tgt))) break;
        }
      }
      __syncthreads();

      float zpre[2];
#pragma unroll
      for (int u = 0; u < 2; ++u)
        zpre[u] = sc_load_f32(zbuf + eb[u] * 1024 + (n0 + ec[u]));

      s16x8 ah[4][4], al[4][4];
#pragma unroll
      for (int ks = 0; ks < 4; ++ks)
#pragma unroll
        for (int mi = 0; mi < 4; ++mi)
          ah[ks][mi] = sc_load_b128(s2 + (size_t)(lr + 16 * mi) * 2048 +
                                    (KB0 + ks * 32 + lg * 8));
#pragma unroll
      for (int ks = 0; ks < 4; ++ks)
#pragma unroll
        for (int mi = 0; mi < 4; ++mi)
          al[ks][mi] = sc_load_b128(s2 + (size_t)(lr + 16 * mi) * 2048 +
                                    (1024 + KB0 + ks * 32 + lg * 8));

      f32x4 acc[4];
#pragma unroll
      for (int mi = 0; mi < 4; ++mi) {
        acc[mi][0] = 0.f; acc[mi][1] = 0.f; acc[mi][2] = 0.f; acc[mi][3] = 0.f;
      }

      asm volatile("s_waitcnt vmcnt(16)" ::: "memory");
      __builtin_amdgcn_sched_barrier(0);
#pragma unroll
      for (int ks = 0; ks < 4; ++ks) {
        int kp = KB0 + ks * 32 + lg * 8;
        s16x8 bfv = *(const s16x8*)(browp + ((kp * 2) ^ bswz));
#pragma unroll
        for (int mi = 0; mi < 4; ++mi)
          acc[mi] = __builtin_amdgcn_mfma_f32_16x16x32_bf16(ah[ks][mi], bfv,
                                                            acc[mi], 0, 0, 0);
      }
#pragma unroll
      for (int ks = 0; ks < 4; ++ks) {
        int kp = 1024 + KB0 + ks * 32 + lg * 8;
        s16x8 bfv = *(const s16x8*)(browp + ((kp * 2) ^ bswz));
#pragma unroll
        for (int mi = 0; mi < 4; ++mi)
          acc[mi] = __builtin_amdgcn_mfma_f32_16x16x32_bf16(ah[ks][mi], bfv,
                                                            acc[mi], 0, 0, 0);
      }
      vm_drain();
      __builtin_amdgcn_sched_barrier(0);
#pragma unroll
      for (int ks = 0; ks < 4; ++ks) {
        int kp = 2048 + KB0 + ks * 32 + lg * 8;
        s16x8 bfv = *(const s16x8*)(browp + ((kp * 2) ^ bswz));
#pragma unroll
        for (int mi = 0; mi < 4; ++mi)
          acc[mi] = __builtin_amdgcn_mfma_f32_16x16x32_bf16(al[ks][mi], bfv,
                                                            acc[mi], 0, 0, 0);
      }
#pragma unroll
      for (int mi = 0; mi < 4; ++mi)
#pragma unroll
        for (int v = 0; v < 4; ++v)
          red[(w * 64 + mi * 16 + lg * 4 + v) * 17 + lr] = acc[mi][v];
      __syncthreads();

#pragma unroll
      for (int u = 0; u < 2; ++u) {
        int b = eb[u], c = ec[u];
        float s = 0.f;
#pragma unroll
        for (int q = 0; q < 8; ++q) s += red[(q * 64 + b) * 17 + c];
        int j = n0 + c;
        float pre = s + xpre[u];
        float ht = tanhf(pre);
        float z = zpre[u];
        float hv = hreg[u];
        float hn = (1.f - z) * hv + z * ht;
        hreg[u] = hn;
        sc_store_f32(h + b * 1024 + j, hn);
        unsigned short hb = f2bf(hn);
        sc_store_u16(h2 + b * 2048 + j, hb);
        sc_store_u16(h2 + b * 2048 + 1024 + j, f2bf(hn - bf2f(hb)));
        out[((size_t)b * T_ + (t0i + tt)) * 1024 + j] = hn;
        if (t0i + tt == T_ - 1)
          out[(size_t)B_ * T_ * 1024 + b * 1024 + j] = hn;
      }
      vm_drain();
      __syncthreads();
      if (tid == 0) sc_store_u32(flagsB + tile, t + 1);
    }
  }
}

extern "C" void kernel_launch(void* const* d_in, const int* in_sizes, int n_in,
                              void* d_out, int out_size, void* d_ws, size_t ws_size,
                              hipStream_t stream) {
  const float* x  = (const float*)d_in[0];
  const float* h0 = (const float*)d_in[1];
  const float* Wz = (const float*)d_in[2];
  const float* bz = (const float*)d_in[3];
  const float* Uz = (const float*)d_in[4];
  const float* Wr = (const float*)d_in[5];
  const float* br = (const float*)d_in[6];
  const float* Ur = (const float*)d_in[7];
  const float* Wh = (const float*)d_in[8];
  const float* bh = (const float*)d_in[9];
  const float* Uh = (const float*)d_in[10];
  float* out = (float*)d_out;

  uint8_t* ws = (uint8_t*)d_ws;
  uint16_t* W2    = (uint16_t*)(ws + 0);          // [3072][1536] bf16
  float*    hbuf  = (float*)   (ws + 9437184);    // [64][1024]
  uint16_t* h2    = (uint16_t*)(ws + 9699328);    // [64][2048]
  uint16_t* s2    = (uint16_t*)(ws + 9961472);    // [64][2048]
  float*    zbuf  = (float*)   (ws + 10223616);   // [64][1024]
  unsigned* flagsA= (unsigned*)(ws + 10485760);   // [128]
  unsigned* flagsB= (unsigned*)(ws + 10486272);   // [64]
  float*    XP    = (float*)   (ws + 10489856);   // [Tc][3][64][1024] fp32

  hipMemsetAsync((void*)flagsA, 0, 1024, stream);

  k_split<<<512, 256, 0, stream>>>(Wz, W2, 9, 1024 * 512);
  k_split<<<512, 256, 0, stream>>>(Wr, W2 + (size_t)1024 * 1536, 9, 1024 * 512);
  k_split<<<512, 256, 0, stream>>>(Wh, W2 + (size_t)2048 * 1536, 9, 1024 * 512);
  k_init<<<64, 256, 0, stream>>>(h0, hbuf, h2);

  size_t avail = (ws_size > 10489856u) ? (ws_size - 10489856u) : 0u;
  long long tcl = (long long)(avail / 786432u);
  int Tc = (tcl > 512) ? 512 : (int)tcl;
  Tc &= ~1;
  if (Tc < 2) Tc = 2;

  for (int t0 = 0; t0 < T_; t0 += Tc) {
    int Tcc = (Tc < T_ - t0) ? Tc : (T_ - t0);
    int MT = (B_ * Tcc) / 128;
    k_proj<<<MT * 24, 256, 0, stream>>>(x, W2, bz, br, bh, XP, t0, Tcc, MT);

    int t0v = t0, tccv = Tcc;
    void* args[] = {(void*)&Uz, (void*)&Ur, (void*)&Uh, (void*)&XP,
                    (void*)&t0v, (void*)&tccv, (void*)&hbuf, (void*)&h2,
                    (void*)&s2, (void*)&zbuf, (void*)&out,
                    (void*)&flagsA, (void*)&flagsB};
    hipLaunchCooperativeKernel((void*)k_recur, dim3(NWG), dim3(512),
                               args, 0, stream);
  }
}

// Round 4
// 15890.154 us; speedup vs baseline: 1.2585x; 1.0937x over previous
//
#include <hip/hip_runtime.h>
#include <hip/hip_bf16.h>
#include <stdint.h>

// GRU B=64 T=512 I=512 H=1024, fp32 in/out.
// bf16 hi/lo 3-pass MFMA numerics (identical to rounds 1-3).
// Round 4: persistent kernel, fence-free producers (sc0sc1 write-through),
// L2-AMPLIFIED consumers (acquire buffer_inv + sc0 cached loads),
// padded flags + sleep-backoff polling, [hi|lo] LDS weights w/ reg reuse.

#define B_ 64
#define T_ 512
#define I_ 512
#define H_ 1024
#define NWG_A 128
#define NWG_B 64
#define NWG 192
#define FSTR 64   // flag padding stride (uints) = 256B

typedef __attribute__((ext_vector_type(4))) float f32x4;
typedef __attribute__((ext_vector_type(8))) short s16x8;

__device__ __forceinline__ unsigned short f2bf(float f) {
  union { float f; uint32_t u; } v; v.f = f;
  uint32_t u = v.u;
  u += 0x7fffu + ((u >> 16) & 1u);   // RNE
  return (unsigned short)(u >> 16);
}
__device__ __forceinline__ float bf2f(unsigned short h) {
  union { uint32_t u; float f; } v; v.u = ((uint32_t)h) << 16;
  return v.f;
}

// ---- system-scope write-through stores (keep L2 clean, visible at L3) ----
__device__ __forceinline__ void sc_store_f32(float* p, float v) {
  asm volatile("global_store_dword %0, %1, off sc0 sc1"
               :: "v"(p), "v"(v) : "memory");
}
__device__ __forceinline__ void sc_store_u16(uint16_t* p, unsigned v) {
  asm volatile("global_store_short %0, %1, off sc0 sc1"
               :: "v"(p), "v"(v) : "memory");
}
__device__ __forceinline__ void sc_store_u32(unsigned* p, unsigned v) {
  asm volatile("global_store_dword %0, %1, off sc0 sc1"
               :: "v"(p), "v"(v) : "memory");
}
// ---- L2-cached consumer loads (bypass L1 only; fresh after buffer_inv) ----
__device__ __forceinline__ s16x8 sc0_load_b128(const uint16_t* p) {
  s16x8 r;
  asm volatile("global_load_dwordx4 %0, %1, off sc0"
               : "=v"(r) : "v"(p) : "memory");
  return r;
}
__device__ __forceinline__ float sc0_load_f32(const float* p) {
  float r;
  asm volatile("global_load_dword %0, %1, off sc0"
               : "=v"(r) : "v"(p) : "memory");
  return r;
}
__device__ __forceinline__ void vm_drain() {
  asm volatile("s_waitcnt vmcnt(0)" ::: "memory");
}

// src [N][K] fp32 -> dst [N][3K] bf16 as [hi | lo | hi] K-blocks. K = 1<<kshift.
__global__ void k_split(const float* __restrict__ src, uint16_t* __restrict__ dst,
                        int kshift, int total) {
  int K = 1 << kshift;
  for (int i = blockIdx.x * blockDim.x + threadIdx.x; i < total;
       i += gridDim.x * blockDim.x) {
    int n = i >> kshift, k = i & (K - 1);
    float f = src[i];
    unsigned short hi = f2bf(f);
    unsigned short lo = f2bf(f - bf2f(hi));
    size_t base = (size_t)n * (3 * K);
    dst[base + k] = hi;
    dst[base + K + k] = lo;
    dst[base + 2 * K + k] = hi;
  }
}

__global__ void k_init(const float* __restrict__ h0, float* __restrict__ h,
                       uint16_t* __restrict__ h2) {
  for (int i = blockIdx.x * blockDim.x + threadIdx.x; i < B_ * H_;
       i += gridDim.x * blockDim.x) {
    float f = h0[i];
    h[i] = f;
    int b = i >> 10, j = i & 1023;
    unsigned short hi = f2bf(f);
    h2[b * 2048 + j] = hi;
    h2[b * 2048 + 1024 + j] = f2bf(f - bf2f(hi));
  }
}

// Projection GEMM (unchanged): XP[tt][gate][b][j] = x@W^T + bias
__global__ __launch_bounds__(256) void k_proj(
    const float* __restrict__ x, const uint16_t* __restrict__ W2,
    const float* __restrict__ bz, const float* __restrict__ br,
    const float* __restrict__ bh,
    float* __restrict__ XP, int t0, int Tc, int MT) {
  __shared__ uint16_t As[128][72];
  __shared__ uint16_t Bs[128][72];
  int bid = blockIdx.x;
  int mt = bid % MT, nt = bid / MT;
  int tid = threadIdx.x;
  int w = tid >> 6, l = tid & 63;
  int wm = w >> 1, wn = w & 1;
  int lr = l & 15, lg = l >> 4;

  int gr[4], gc8[4];
  const float* asrc[4];
  const uint16_t* bsrc[4];
#pragma unroll
  for (int g = 0; g < 4; ++g) {
    int gran = tid + 256 * g;
    int r = gran >> 3, c8 = gran & 7;
    gr[g] = r; gc8[g] = c8;
    int n = mt * 128 + r;
    int b = n / Tc, tt = n % Tc;
    asrc[g] = x + ((size_t)b * T_ + (t0 + tt)) * I_;
    bsrc[g] = W2 + (size_t)(nt * 128 + r) * 1536;
  }

  f32x4 acc[4][4];
#pragma unroll
  for (int mi = 0; mi < 4; ++mi)
#pragma unroll
    for (int ni = 0; ni < 4; ++ni) {
      acc[mi][ni][0] = 0.f; acc[mi][ni][1] = 0.f;
      acc[mi][ni][2] = 0.f; acc[mi][ni][3] = 0.f;
    }

  float4 pa[8];
  uint4 pb[4];
#pragma unroll
  for (int g = 0; g < 4; ++g) {
    int kp = gc8[g] * 8;
    int xc = kp & 511;
    pa[2 * g] = *(const float4*)(asrc[g] + xc);
    pa[2 * g + 1] = *(const float4*)(asrc[g] + xc + 4);
    pb[g] = *(const uint4*)(bsrc[g] + kp);
  }

  for (int it = 0; it < 24; ++it) {
    __syncthreads();
    {
      int k0 = it * 64;
#pragma unroll
      for (int g = 0; g < 4; ++g) {
        int kp = k0 + gc8[g] * 8;
        bool lofl = (kp >= 1024);
        const float* pf = (const float*)&pa[2 * g];
        s16x8 v;
#pragma unroll
        for (int j = 0; j < 8; ++j) {
          float f = pf[j];
          unsigned short hi = f2bf(f);
          v[j] = (short)(lofl ? f2bf(f - bf2f(hi)) : hi);
        }
        *(s16x8*)(&As[gr[g]][gc8[g] * 8]) = v;
        *(uint4*)(&Bs[gr[g]][gc8[g] * 8]) = pb[g];
      }
    }
    if (it + 1 < 24) {
      int k0 = (it + 1) * 64;
#pragma unroll
      for (int g = 0; g < 4; ++g) {
        int kp = k0 + gc8[g] * 8;
        int xc = kp & 511;
        pa[2 * g] = *(const float4*)(asrc[g] + xc);
        pa[2 * g + 1] = *(const float4*)(asrc[g] + xc + 4);
        pb[g] = *(const uint4*)(bsrc[g] + kp);
      }
    }
    __syncthreads();
#pragma unroll
    for (int kk = 0; kk < 64; kk += 32) {
      s16x8 af[4], bf[4];
#pragma unroll
      for (int mi = 0; mi < 4; ++mi)
        af[mi] = *(const s16x8*)(&As[wm * 64 + mi * 16 + lr][kk + lg * 8]);
#pragma unroll
      for (int ni = 0; ni < 4; ++ni)
        bf[ni] = *(const s16x8*)(&Bs[wn * 64 + ni * 16 + lr][kk + lg * 8]);
#pragma unroll
      for (int mi = 0; mi < 4; ++mi)
#pragma unroll
        for (int ni = 0; ni < 4; ++ni)
          acc[mi][ni] = __builtin_amdgcn_mfma_f32_16x16x32_bf16(
              af[mi], bf[ni], acc[mi][ni], 0, 0, 0);
    }
  }

  int g_ = (nt * 128) >> 10;
  const float* bias = (g_ == 0) ? bz : ((g_ == 1) ? br : bh);
#pragma unroll
  for (int ni = 0; ni < 4; ++ni) {
    int col = nt * 128 + wn * 64 + ni * 16 + lr;
    int jc = col & 1023;
    float bv = bias[jc];
#pragma unroll
    for (int mi = 0; mi < 4; ++mi) {
      int nrow = mt * 128 + wm * 64 + mi * 16 + lg * 4;
      int b = nrow / Tc, tt = nrow % Tc;
#pragma unroll
      for (int v = 0; v < 4; ++v) {
        XP[((size_t)((tt * 3 + g_) * 64 + b)) * 1024 + jc] = acc[mi][ni][v] + bv;
        if (++tt == Tc) { tt = 0; ++b; }
      }
    }
  }
}

// ---- persistent recurrence kernel ----
// wgs 0..63: phase A z-cols; 64..127: phase A r-cols (produce s2);
// 128..191: phase B h~-cols (h slice in registers).
// Handoff: producers write-through (sc0sc1) + padded flag; consumers poll
// (sc0sc1 + s_sleep backoff), one agent-acquire (buffer_inv) per wg, then
// L2-cached sc0 loads (amplified across the XCD).
__global__ __launch_bounds__(512) void k_recur(
    const float* __restrict__ Uz, const float* __restrict__ Ur,
    const float* __restrict__ Uh, const float* __restrict__ XP,
    int t0i, int Tcc, float* __restrict__ h, uint16_t* __restrict__ h2,
    uint16_t* __restrict__ s2, float* __restrict__ zbuf,
    float* __restrict__ out, unsigned* __restrict__ flagsA,
    unsigned* __restrict__ flagsB) {
  __shared__ uint16_t Wl[16 * 2048];       // [hi(1024) | lo(1024)] per U-row
  __shared__ float red[8 * 64 * 17];

  const int tid = threadIdx.x;
  const int w = tid >> 6, l = tid & 63;
  const int lr = l & 15, lg = l >> 4;
  const int bid = blockIdx.x;
  const bool isA = (bid < NWG_A);
  const int tile = isA ? bid : (bid - NWG_A);
  const int n0 = tile * 16;
  const bool isR = isA && (n0 >= 1024);

  // stage weights fp32 -> [hi|lo] bf16, XOR-swizzled rows (once)
  const float* src = isA ? ((n0 < 1024) ? (Uz + (size_t)n0 * 1024)
                                        : (Ur + (size_t)(n0 - 1024) * 1024))
                         : (Uh + (size_t)n0 * 1024);
  for (int i = tid; i < 2048; i += 512) {
    int r = i >> 7;
    int k8 = (i & 127) * 8;
    const float* p = src + r * 1024 + k8;
    s16x8 hi8, lo8;
#pragma unroll
    for (int j = 0; j < 8; ++j) {
      float f = p[j];
      unsigned short hb = f2bf(f);
      hi8[j] = (short)hb;
      lo8[j] = (short)f2bf(f - bf2f(hb));
    }
    uint8_t* rowp = (uint8_t*)Wl + r * 4096;
    int swz = (r & 7) << 4;
    *(s16x8*)(rowp + ((k8 * 2) ^ swz)) = hi8;
    *(s16x8*)(rowp + (((1024 + k8) * 2) ^ swz)) = lo8;
  }
  __syncthreads();

  const int KB0 = w * 128;
  const int bswz = (lr & 7) << 4;
  const uint8_t* browp = (const uint8_t*)Wl + lr * 4096;

  int eb[2], ec[2];
#pragma unroll
  for (int u = 0; u < 2; ++u) {
    int e = tid + u * 512;
    eb[u] = e >> 4; ec[u] = e & 15;
  }

  // B-wgs: h slice lives in registers across all steps
  float hreg[2];
  if (!isA) {
#pragma unroll
    for (int u = 0; u < 2; ++u)
      hreg[u] = h[eb[u] * 1024 + (n0 + ec[u])];
  }

  for (int tt = 0; tt < Tcc; ++tt) {
    const unsigned t = (unsigned)(t0i + tt);

    // XP prefetch (plain cached; XP immutable during this launch)
    float xpre[2];
    {
      int gate = isA ? (isR ? 1 : 0) : 2;
#pragma unroll
      for (int u = 0; u < 2; ++u) {
        int jc = (n0 + ec[u]) & 1023;
        xpre[u] = XP[((size_t)(tt * 3 + gate) * 64 + eb[u]) * 1024 + jc];
      }
    }

    if (isA) {
      // wait for phase B of step t-1
      if (t > 0 && w == 0) {
        const unsigned* fp = flagsB + (size_t)l * FSTR;
        for (;;) {
          unsigned f;
          asm volatile("global_load_dword %0, %1, off sc0 sc1\n\t"
                       "s_waitcnt vmcnt(0)"
                       : "=v"(f) : "v"(fp) : "memory");
          if (__all(f >= t)) break;
          __builtin_amdgcn_s_sleep(4);
        }
        if (l == 0)
          (void)__hip_atomic_load(flagsB, __ATOMIC_ACQUIRE,
                                  __HIP_MEMORY_SCOPE_AGENT);  // buffer_inv
        vm_drain();
      }
      __syncthreads();

      float hpre[2];
      if (isR) {
#pragma unroll
        for (int u = 0; u < 2; ++u)
          hpre[u] = sc0_load_f32(h + eb[u] * 1024 + (n0 - 1024 + ec[u]));
      }

      s16x8 ah[4][4], al[4][4];
#pragma unroll
      for (int ks = 0; ks < 4; ++ks)
#pragma unroll
        for (int mi = 0; mi < 4; ++mi)
          ah[ks][mi] = sc0_load_b128(h2 + (size_t)(lr + 16 * mi) * 2048 +
                                     (KB0 + ks * 32 + lg * 8));
#pragma unroll
      for (int ks = 0; ks < 4; ++ks)
#pragma unroll
        for (int mi = 0; mi < 4; ++mi)
          al[ks][mi] = sc0_load_b128(h2 + (size_t)(lr + 16 * mi) * 2048 +
                                     (1024 + KB0 + ks * 32 + lg * 8));

      f32x4 acc[4];
#pragma unroll
      for (int mi = 0; mi < 4; ++mi) {
        acc[mi][0] = 0.f; acc[mi][1] = 0.f; acc[mi][2] = 0.f; acc[mi][3] = 0.f;
      }

      asm volatile("s_waitcnt vmcnt(16)" ::: "memory");
      __builtin_amdgcn_sched_barrier(0);
      s16x8 bfv0[4];
#pragma unroll
      for (int ks = 0; ks < 4; ++ks) {   // seg0: A_hi * B_hi
        int kp = KB0 + ks * 32 + lg * 8;
        bfv0[ks] = *(const s16x8*)(browp + ((kp * 2) ^ bswz));
#pragma unroll
        for (int mi = 0; mi < 4; ++mi)
          acc[mi] = __builtin_amdgcn_mfma_f32_16x16x32_bf16(ah[ks][mi], bfv0[ks],
                                                            acc[mi], 0, 0, 0);
      }
#pragma unroll
      for (int ks = 0; ks < 4; ++ks) {   // seg1: A_hi * B_lo
        int kp = KB0 + ks * 32 + lg * 8;
        s16x8 bfv = *(const s16x8*)(browp + (((1024 + kp) * 2) ^ bswz));
#pragma unroll
        for (int mi = 0; mi < 4; ++mi)
          acc[mi] = __builtin_amdgcn_mfma_f32_16x16x32_bf16(ah[ks][mi], bfv,
                                                            acc[mi], 0, 0, 0);
      }
      vm_drain();
      __builtin_amdgcn_sched_barrier(0);
#pragma unroll
      for (int ks = 0; ks < 4; ++ks)     // seg2: A_lo * B_hi (reg reuse)
#pragma unroll
        for (int mi = 0; mi < 4; ++mi)
          acc[mi] = __builtin_amdgcn_mfma_f32_16x16x32_bf16(al[ks][mi], bfv0[ks],
                                                            acc[mi], 0, 0, 0);
#pragma unroll
      for (int mi = 0; mi < 4; ++mi)
#pragma unroll
        for (int v = 0; v < 4; ++v)
          red[(w * 64 + mi * 16 + lg * 4 + v) * 17 + lr] = acc[mi][v];
      __syncthreads();

#pragma unroll
      for (int u = 0; u < 2; ++u) {
        int b = eb[u], c = ec[u];
        float s = 0.f;
#pragma unroll
        for (int q = 0; q < 8; ++q) s += red[(q * 64 + b) * 17 + c];
        float pre = s + xpre[u];
        if (!isR) {
          int n = n0 + c;
          sc_store_f32(zbuf + b * 1024 + n, 1.f / (1.f + __expf(-pre)));
        } else {
          int j = n0 - 1024 + c;
          float r = 1.f / (1.f + __expf(-pre));
          float sv = r * hpre[u];
          unsigned short hb = f2bf(sv);
          sc_store_u16(s2 + b * 2048 + j, hb);
          sc_store_u16(s2 + b * 2048 + 1024 + j, f2bf(sv - bf2f(hb)));
        }
      }
      vm_drain();
      __syncthreads();
      if (tid == 0) sc_store_u32(flagsA + (size_t)tile * FSTR, t + 1);
    } else {
      // ---- phase B ----
      if (w == 0) {
        const unsigned* fp0 = flagsA + (size_t)(2 * l) * FSTR;
        const unsigned* fp1 = flagsA + (size_t)(2 * l + 1) * FSTR;
        unsigned tgt = t + 1;
        for (;;) {
          unsigned f0, f1;
          asm volatile("global_load_dword %0, %2, off sc0 sc1\n\t"
                       "global_load_dword %1, %3, off sc0 sc1\n\t"
                       "s_waitcnt vmcnt(0)"
                       : "=v"(f0), "=v"(f1) : "v"(fp0), "v"(fp1) : "memory");
          if (__all((f0 >= tgt) && (f1 >= tgt))) break;
          __builtin_amdgcn_s_sleep(4);
        }
        if (l == 0)
          (void)__hip_atomic_load(flagsA, __ATOMIC_ACQUIRE,
                                  __HIP_MEMORY_SCOPE_AGENT);  // buffer_inv
        vm_drain();
      }
      __syncthreads();

      float zpre[2];
#pragma unroll
      for (int u = 0; u < 2; ++u)
        zpre[u] = sc0_load_f32(zbuf + eb[u] * 1024 + (n0 + ec[u]));

      s16x8 ah[4][4], al[4][4];
#pragma unroll
      for (int ks = 0; ks < 4; ++ks)
#pragma unroll
        for (int mi = 0; mi < 4; ++mi)
          ah[ks][mi] = sc0_load_b128(s2 + (size_t)(lr + 16 * mi) * 2048 +
                                     (KB0 + ks * 32 + lg * 8));
#pragma unroll
      for (int ks = 0; ks < 4; ++ks)
#pragma unroll
        for (int mi = 0; mi < 4; ++mi)
          al[ks][mi] = sc0_load_b128(s2 + (size_t)(lr + 16 * mi) * 2048 +
                                     (1024 + KB0 + ks * 32 + lg * 8));

      f32x4 acc[4];
#pragma unroll
      for (int mi = 0; mi < 4; ++mi) {
        acc[mi][0] = 0.f; acc[mi][1] = 0.f; acc[mi][2] = 0.f; acc[mi][3] = 0.f;
      }

      asm volatile("s_waitcnt vmcnt(16)" ::: "memory");
      __builtin_amdgcn_sched_barrier(0);
      s16x8 bfv0[4];
#pragma unroll
      for (int ks = 0; ks < 4; ++ks) {
        int kp = KB0 + ks * 32 + lg * 8;
        bfv0[ks] = *(const s16x8*)(browp + ((kp * 2) ^ bswz));
#pragma unroll
        for (int mi = 0; mi < 4; ++mi)
          acc[mi] = __builtin_amdgcn_mfma_f32_16x16x32_bf16(ah[ks][mi], bfv0[ks],
                                                            acc[mi], 0, 0, 0);
      }
#pragma unroll
      for (int ks = 0; ks < 4; ++ks) {
        int kp = KB0 + ks * 32 + lg * 8;
        s16x8 bfv = *(const s16x8*)(browp + (((1024 + kp) * 2) ^ bswz));
#pragma unroll
        for (int mi = 0; mi < 4; ++mi)
          acc[mi] = __builtin_amdgcn_mfma_f32_16x16x32_bf16(ah[ks][mi], bfv,
                                                            acc[mi], 0, 0, 0);
      }
      vm_drain();
      __builtin_amdgcn_sched_barrier(0);
#pragma unroll
      for (int ks = 0; ks < 4; ++ks)
#pragma unroll
        for (int mi = 0; mi < 4; ++mi)
          acc[mi] = __builtin_amdgcn_mfma_f32_16x16x32_bf16(al[ks][mi], bfv0[ks],
                                                            acc[mi], 0, 0, 0);
#pragma unroll
      for (int mi = 0; mi < 4; ++mi)
#pragma unroll
        for (int v = 0; v < 4; ++v)
          red[(w * 64 + mi * 16 + lg * 4 + v) * 17 + lr] = acc[mi][v];
      __syncthreads();

#pragma unroll
      for (int u = 0; u < 2; ++u) {
        int b = eb[u], c = ec[u];
        float s = 0.f;
#pragma unroll
        for (int q = 0; q < 8; ++q) s += red[(q * 64 + b) * 17 + c];
        int j = n0 + c;
        float pre = s + xpre[u];
        float ht = tanhf(pre);
        float z = zpre[u];
        float hv = hreg[u];
        float hn = (1.f - z) * hv + z * ht;
        hreg[u] = hn;
        sc_store_f32(h + b * 1024 + j, hn);
        unsigned short hb = f2bf(hn);
        sc_store_u16(h2 + b * 2048 + j, hb);
        sc_store_u16(h2 + b * 2048 + 1024 + j, f2bf(hn - bf2f(hb)));
        sc_store_f32(out + ((size_t)b * T_ + (t0i + tt)) * 1024 + j, hn);
        if (t0i + tt == T_ - 1)
          sc_store_f32(out + (size_t)B_ * T_ * 1024 + b * 1024 + j, hn);
      }
      vm_drain();
      __syncthreads();
      if (tid == 0) sc_store_u32(flagsB + (size_t)tile * FSTR, t + 1);
    }
  }
}

extern "C" void kernel_launch(void* const* d_in, const int* in_sizes, int n_in,
                              void* d_out, int out_size, void* d_ws, size_t ws_size,
                              hipStream_t stream) {
  const float* x  = (const float*)d_in[0];
  const float* h0 = (const float*)d_in[1];
  const float* Wz = (const float*)d_in[2];
  const float* bz = (const float*)d_in[3];
  const float* Uz = (const float*)d_in[4];
  const float* Wr = (const float*)d_in[5];
  const float* br = (const float*)d_in[6];
  const float* Ur = (const float*)d_in[7];
  const float* Wh = (const float*)d_in[8];
  const float* bh = (const float*)d_in[9];
  const float* Uh = (const float*)d_in[10];
  float* out = (float*)d_out;

  uint8_t* ws = (uint8_t*)d_ws;
  uint16_t* W2    = (uint16_t*)(ws + 0);          // [3072][1536] bf16
  float*    hbuf  = (float*)   (ws + 9437184);    // [64][1024]
  uint16_t* h2    = (uint16_t*)(ws + 9699328);    // [64][2048]
  uint16_t* s2    = (uint16_t*)(ws + 9961472);    // [64][2048]
  float*    zbuf  = (float*)   (ws + 10223616);   // [64][1024]
  unsigned* flagsA= (unsigned*)(ws + 10485760);   // 128 x 256B
  unsigned* flagsB= (unsigned*)(ws + 10518528);   // 64 x 256B
  float*    XP    = (float*)   (ws + 10534912);   // [Tc][3][64][1024] fp32

  hipMemsetAsync((void*)flagsA, 0, 49152, stream);

  k_split<<<512, 256, 0, stream>>>(Wz, W2, 9, 1024 * 512);
  k_split<<<512, 256, 0, stream>>>(Wr, W2 + (size_t)1024 * 1536, 9, 1024 * 512);
  k_split<<<512, 256, 0, stream>>>(Wh, W2 + (size_t)2048 * 1536, 9, 1024 * 512);
  k_init<<<64, 256, 0, stream>>>(h0, hbuf, h2);

  size_t avail = (ws_size > 10534912u) ? (ws_size - 10534912u) : 0u;
  long long tcl = (long long)(avail / 786432u);
  int Tc = (tcl > 512) ? 512 : (int)tcl;
  Tc &= ~1;
  if (Tc < 2) Tc = 2;

  for (int t0 = 0; t0 < T_; t0 += Tc) {
    int Tcc = (Tc < T_ - t0) ? Tc : (T_ - t0);
    int MT = (B_ * Tcc) / 128;
    k_proj<<<MT * 24, 256, 0, stream>>>(x, W2, bz, br, bh, XP, t0, Tcc, MT);

    int t0v = t0, tccv = Tcc;
    void* args[] = {(void*)&Uz, (void*)&Ur, (void*)&Uh, (void*)&XP,
                    (void*)&t0v, (void*)&tccv, (void*)&hbuf, (void*)&h2,
                    (void*)&s2, (void*)&zbuf, (void*)&out,
                    (void*)&flagsA, (void*)&flagsB};
    hipLaunchCooperativeKernel((void*)k_recur, dim3(NWG), dim3(512),
                               args, 0, stream);
  }
}